// Round 4
// baseline (62.102 us; speedup 1.0000x reference)
//
#include <hip/hip_runtime.h>
#include <hip/hip_fp16.h>

#define BB 16
#define DD 512
#define NN 4096
#define KK 32
#define TN 64          // n-tile per block
#define NTILES 64      // tiles per batch
#define NBLK (BB*NTILES)   // 1024 blocks
#define ROWL 72        // xb row length in bf16 elems (144 B)
#define ROWA 72        // a_t row length

typedef unsigned short u16;
typedef __attribute__((ext_vector_type(8))) short short8v;
typedef __attribute__((ext_vector_type(4))) float f32x4;

// swizzled LDS index: 8-elem (16 B) chunks, chunk column XORed with d-bits
__device__ __forceinline__ int xidx(int d, int n) {
    return d * ROWL + ((((n >> 3) ^ ((d >> 3) & 7)) << 3) | (n & 7));
}

__device__ __forceinline__ unsigned f2bf(float f) {
    union { float f; unsigned u; } v; v.f = f;
    unsigned r = v.u + 0x7fff + ((v.u >> 16) & 1);   // RNE
    return r >> 16;
}

// ---------------- K0: prep codewords (bf16 copy, c2, s2); 1 wave per k ----
__global__ void k0_prep(const float* __restrict__ cw, const float* __restrict__ scale,
                        u16* __restrict__ c_bf, float* __restrict__ c2,
                        float* __restrict__ s2) {
    const int k = blockIdx.x;       // 32 blocks
    const int l = threadIdx.x;      // 64 threads
    const float* row = cw + k * DD;
    float s = 0.f;
#pragma unroll
    for (int j = 0; j < 8; ++j) {
        float v = row[j * 64 + l];
        s += v * v;
        c_bf[k * DD + j * 64 + l] = (u16)f2bf(v);
    }
#pragma unroll
    for (int off = 32; off; off >>= 1) s += __shfl_xor(s, off);
    if (l == 0) { c2[k] = s; float sc = scale[k]; s2[k] = sc * sc; }
}

// ---------------- K1: fused main kernel (2 blocks/CU) ----------------
template <typename PART>
__global__ __launch_bounds__(512, 4)
void k1_fused(const float* __restrict__ x, const u16* __restrict__ c_bf,
              const float* __restrict__ c2g, const float* __restrict__ s2g,
              float* __restrict__ ws_asum, PART* __restrict__ ws_e) {
    extern __shared__ char smem[];
    u16*   xb      = (u16*)smem;                       // [512][72] bf16: 73728 B
    u16*   a_t     = xb + DD * ROWL;                   // [32][72]  bf16:  4608 B
    float* x2_part = (float*)(a_t + KK * ROWA);        // [8][64]:   2048 B
    float* x2      = x2_part + 8 * TN;                 // [64]
    float* asum_p  = x2 + TN;                          // [4][32]

    const int t = threadIdx.x;
    const int l = t & 63, w = t >> 6;        // lane, wave (8 waves)
    const int g = l >> 4, li = l & 15;       // 16-lane group, group-lane
    const int blk = blockIdx.x;
    const int b = blk >> 6, tile = blk & 63;
    const int n0 = tile * TN;
    const float* xg = x + ((size_t)b * DD) * NN + n0;

    // ---- stage x tile -> LDS bf16 (swizzled); deep-pipelined loads ----
    {
        const int c4 = t & 15, rg = t >> 4;  // n = 4*c4, d = j*32 + rg
        const float* bp = xg + (size_t)rg * NN + 4 * c4;
        float4 v[16];
#pragma unroll
        for (int j = 0; j < 16; ++j) v[j] = *(const float4*)(bp + (size_t)(j * 32) * NN);
        float p0 = 0, p1 = 0, p2 = 0, p3 = 0;
#pragma unroll
        for (int j = 0; j < 16; ++j) {
            const int d = j * 32 + rg;
            uint2 pk;
            pk.x = f2bf(v[j].x) | (f2bf(v[j].y) << 16);
            pk.y = f2bf(v[j].z) | (f2bf(v[j].w) << 16);
            *(uint2*)(xb + xidx(d, 4 * c4)) = pk;
            p0 += v[j].x * v[j].x; p1 += v[j].y * v[j].y;
            p2 += v[j].z * v[j].z; p3 += v[j].w * v[j].w;
        }
        // pre-reduce x2 across the wave's 4 row-groups (lanes sharing c4)
        p0 += __shfl_xor(p0, 16); p0 += __shfl_xor(p0, 32);
        p1 += __shfl_xor(p1, 16); p1 += __shfl_xor(p1, 32);
        p2 += __shfl_xor(p2, 16); p2 += __shfl_xor(p2, 32);
        p3 += __shfl_xor(p3, 16); p3 += __shfl_xor(p3, 32);
        if (l < 16) {
            x2_part[w * TN + 4 * l + 0] = p0;
            x2_part[w * TN + 4 * l + 1] = p1;
            x2_part[w * TN + 4 * l + 2] = p2;
            x2_part[w * TN + 4 * l + 3] = p3;
        }
    }
    __syncthreads();

    // x2 final reduce on wave 4 (concurrent with phase A on waves 0-3)
    if (t >= 256 && t < 256 + TN) {
        const int n = t - 256;
        float s = 0.f;
        #pragma unroll
        for (int ww = 0; ww < 8; ++ww) s += x2_part[ww * TN + n];
        x2[n] = s;
    }

    // ---- phase A (waves 0-3): pre-logits = c . x  out[k=32][n=16 per wave]
    f32x4 accA0 = {0.f, 0.f, 0.f, 0.f}, accA1 = {0.f, 0.f, 0.f, 0.f};
    if (w < 4) {
        const int nloc = w * 16 + li;
        for (int ch = 0; ch < 16; ++ch) {
            const int dbase = ch * 32 + g * 8;
            const u16* p = xb + xidx(dbase, nloc);
            short8v bf;
            #pragma unroll
            for (int j = 0; j < 8; ++j) bf[j] = (short)p[j * ROWL];
            short8v a0 = *(const short8v*)(c_bf + (0 * 16 + li) * DD + dbase);
            short8v a1 = *(const short8v*)(c_bf + (1 * 16 + li) * DD + dbase);
            accA0 = __builtin_amdgcn_mfma_f32_16x16x32_bf16(a0, bf, accA0, 0, 0, 0);
            accA1 = __builtin_amdgcn_mfma_f32_16x16x32_bf16(a1, bf, accA1, 0, 0, 0);
        }
    }
    __syncthreads();

    // ---- softmax over k (waves 0-3, one n-column per lane) ----
    if (w < 4) {
        const int nloc = w * 16 + li;
        const float x2v = x2[nloc];
        float sl[8];
        float mx = -3.4e38f;
        #pragma unroll
        for (int r = 0; r < 4; ++r) {
            int k0 = 4 * g + r, k1 = 16 + 4 * g + r;
            float v0 = s2g[k0] * (x2v - 2.f * accA0[r] + c2g[k0]);
            float v1 = s2g[k1] * (x2v - 2.f * accA1[r] + c2g[k1]);
            sl[r] = v0; sl[4 + r] = v1;
            mx = fmaxf(mx, fmaxf(v0, v1));
        }
        mx = fmaxf(mx, __shfl_xor(mx, 16));
        mx = fmaxf(mx, __shfl_xor(mx, 32));
        float sum = 0.f;
        #pragma unroll
        for (int i = 0; i < 8; ++i) { sl[i] = __expf(sl[i] - mx); sum += sl[i]; }
        sum += __shfl_xor(sum, 16);
        sum += __shfl_xor(sum, 32);
        const float inv = 1.f / sum;
        #pragma unroll
        for (int i = 0; i < 8; ++i) {
            float a = sl[i] * inv;
            int k = (i < 4) ? (4 * g + i) : (16 + 4 * g + (i - 4));
            a_t[k * ROWA + nloc] = (u16)f2bf(a);
            float s = a;
            s += __shfl_xor(s, 1); s += __shfl_xor(s, 2);
            s += __shfl_xor(s, 4); s += __shfl_xor(s, 8);
            if (li == 0) asum_p[w * KK + k] = s;   // sum over this wave's 16 n
        }
    }
    __syncthreads();

    // asum partial for this block -> ws (overlaps phase B)
    if (t < KK) {
        float s = 0.f;
        #pragma unroll
        for (int ww = 0; ww < 4; ++ww) s += asum_p[ww * KK + t];
        ws_asum[(size_t)blk * KK + t] = s;
    }

    // ---- phase B (all 8 waves): e_partial[k-tile][d: 128 per wave] ----
    const int kt = w >> 2, dblk = w & 3;
    f32x4 accB[8];
    #pragma unroll
    for (int dt = 0; dt < 8; ++dt) accB[dt] = (f32x4){0.f, 0.f, 0.f, 0.f};

    #pragma unroll
    for (int ch = 0; ch < 2; ++ch) {
        const int nb = ch * 32 + g * 8;
        short8v af = *(const short8v*)(a_t + (kt * 16 + li) * ROWA + nb);
        #pragma unroll
        for (int dt = 0; dt < 8; ++dt) {
            const int d = dblk * 128 + dt * 16 + li;
            short8v xf = *(const short8v*)(xb + xidx(d, nb));
            accB[dt] = __builtin_amdgcn_mfma_f32_16x16x32_bf16(af, xf, accB[dt], 0, 0, 0);
        }
    }

    // ---- write e partials ----
    const size_t ebase = (size_t)blk * KK * DD;
    #pragma unroll
    for (int dt = 0; dt < 8; ++dt)
        #pragma unroll
        for (int r = 0; r < 4; ++r) {
            int k = kt * 16 + 4 * g + r;
            int d = dblk * 128 + dt * 16 + li;
            ws_e[ebase + (size_t)k * DD + d] = (PART)(accB[dt][r]);
        }
}

// ---------------- K2: reduce partials (half2), subtract asum*c ----------
__global__ void k2_reduce_h(const __half2* __restrict__ ws_e, const float* __restrict__ ws_asum,
                            const float* __restrict__ cw, float* __restrict__ out) {
    int tid = blockIdx.x * blockDim.x + threadIdx.x;   // 131072
    int d2 = tid & 255;
    int k = (tid >> 8) & (KK - 1);
    int b = tid >> 13;
    const __half2* pe = ws_e + ((size_t)(b * NTILES) * KK + k) * 256 + d2;
    const float* pa = ws_asum + b * NTILES * KK + k;
    float s0 = 0.f, s1 = 0.f, as = 0.f;
    for (int tl = 0; tl < NTILES; ++tl) {
        float2 f = __half22float2(pe[(size_t)tl * KK * 256]);
        s0 += f.x; s1 += f.y;
        as += pa[tl * KK];
    }
    int d = d2 * 2;
    float c0 = cw[k * DD + d], c1 = cw[k * DD + d + 1];
    float2 o; o.x = s0 - as * c0; o.y = s1 - as * c1;
    *(float2*)(out + ((size_t)(b * KK + k) * DD + d)) = o;
}

__global__ void k2_reduce_f(const float* __restrict__ ws_e, const float* __restrict__ ws_asum,
                            const float* __restrict__ cw, float* __restrict__ out) {
    int tid = blockIdx.x * blockDim.x + threadIdx.x;   // 262144
    int d = tid & (DD - 1);
    int k = (tid >> 9) & (KK - 1);
    int b = tid >> 14;
    float s = 0.f, as = 0.f;
    for (int tl = 0; tl < NTILES; ++tl) {
        int blk = b * NTILES + tl;
        s += ws_e[((size_t)blk * KK + k) * DD + d];
        as += ws_asum[(size_t)blk * KK + k];
    }
    out[tid] = s - as * cw[k * DD + d];
}

extern "C" void kernel_launch(void* const* d_in, const int* in_sizes, int n_in,
                              void* d_out, int out_size, void* d_ws, size_t ws_size,
                              hipStream_t stream) {
    const float* x = (const float*)d_in[0];
    const float* cw = (const float*)d_in[1];
    const float* scale = (const float*)d_in[2];
    float* out = (float*)d_out;

    char* ws = (char*)d_ws;
    u16*   c_bf    = (u16*)ws;                  // 32768 B
    float* c2      = (float*)(ws + 32768);
    float* s2      = (float*)(ws + 32896);
    float* ws_asum = (float*)(ws + 33024);      // 1024*32*4 = 131072 B
    char*  e_ptr   = ws + 164096;

    const size_t lds = (size_t)(DD * ROWL + KK * ROWA) * 2 + (8 * TN + TN + 4 * KK) * 4;
    const size_t need_h = 164096 + (size_t)NBLK * KK * DD * sizeof(__half);

    k0_prep<<<KK, 64, 0, stream>>>(cw, scale, c_bf, c2, s2);
    if (ws_size >= need_h) {
        k1_fused<__half><<<NBLK, 512, lds, stream>>>(x, c_bf, c2, s2, ws_asum, (__half*)e_ptr);
        k2_reduce_h<<<(BB * KK * 256) / 256, 256, 0, stream>>>((const __half2*)e_ptr, ws_asum, cw, out);
    } else {
        k1_fused<float><<<NBLK, 512, lds, stream>>>(x, c_bf, c2, s2, ws_asum, (float*)e_ptr);
        k2_reduce_f<<<(BB * KK * DD) / 256, 256, 0, stream>>>((const float*)e_ptr, ws_asum, cw, out);
    }
}

// Round 5
// 58.018 us; speedup vs baseline: 1.0704x; 1.0704x over previous
//
#include <hip/hip_runtime.h>
#include <hip/hip_fp16.h>

#define BB 16
#define DD 512
#define NN 4096
#define KK 32
#define TNS 64         // n per subtile
#define SUBT 4         // subtiles per block (block owns 256 n)
#define NGRP 16        // n-groups (blocks) per batch
#define NBLK (BB*NGRP) // 256 blocks = 1 per CU
#define ROWL 72        // LDS row length (bf16 elems), 144 B
#define ROWA 72
#define XBUF (DD*ROWL) // 36864 elems per x buffer

typedef unsigned short u16;
typedef __attribute__((ext_vector_type(8))) short short8v;
typedef __attribute__((ext_vector_type(4))) float f32x4;

// swizzled LDS index: 8-elem (16 B) chunks, chunk column XORed with d-bits
__device__ __forceinline__ int xidx(int d, int n) {
    return d * ROWL + ((((n >> 3) ^ ((d >> 3) & 7)) << 3) | (n & 7));
}

__device__ __forceinline__ unsigned f2bf(float f) {
    union { float f; unsigned u; } v; v.f = f;
    unsigned r = v.u + 0x7fff + ((v.u >> 16) & 1);   // RNE
    return r >> 16;
}

// ---------------- K0: prep codewords (bf16 copy, c2, s2); 1 wave per k ----
__global__ void k0_prep(const float* __restrict__ cw, const float* __restrict__ scale,
                        u16* __restrict__ c_bf, float* __restrict__ c2,
                        float* __restrict__ s2) {
    const int k = blockIdx.x;       // 32 blocks
    const int l = threadIdx.x;      // 64 threads
    const float* row = cw + k * DD;
    float s = 0.f;
#pragma unroll
    for (int j = 0; j < 8; ++j) {
        float v = row[j * 64 + l];
        s += v * v;
        c_bf[k * DD + j * 64 + l] = (u16)f2bf(v);
    }
#pragma unroll
    for (int off = 32; off; off >>= 1) s += __shfl_xor(s, off);
    if (l == 0) { c2[k] = s; float sc = scale[k]; s2[k] = sc * sc; }
}

// ---------------- K1: fused, pipelined across 4 subtiles ----------------
template <typename PART>
__global__ __launch_bounds__(512, 2)
void k1_fused(const float* __restrict__ x, const u16* __restrict__ c_bf,
              const float* __restrict__ c2g, const float* __restrict__ s2g,
              float* __restrict__ ws_asum, PART* __restrict__ ws_e) {
    extern __shared__ char smem[];
    u16*   xb0     = (u16*)smem;                 // [512][72] bf16, 73728 B
    u16*   xb1     = xb0 + XBUF;                 // second buffer
    u16*   a_t     = xb1 + XBUF;                 // [32][72] bf16, 4608 B
    float* x2_part = (float*)(a_t + KK * ROWA);  // [8][64]
    float* x2      = x2_part + 8 * TNS;          // [64]
    float* asum_p  = x2 + TNS;                   // [4][32]

    const int t = threadIdx.x;
    const int l = t & 63, w = t >> 6;        // lane, wave (8 waves)
    const int g = l >> 4, li = l & 15;       // 16-lane group, group-lane
    const int blk = blockIdx.x;
    const int b = blk >> 4, grp = blk & 15;
    const int n0 = grp * 256;
    const float* xg = x + (size_t)b * DD * NN + n0;
    const int c4 = t & 15, rg = t >> 4;      // stage: n-seg, row-group (32)

    // preload per-lane softmax constants (k = 4g+r and 16+4g+r)
    float s2r[8], c2r[8];
#pragma unroll
    for (int r = 0; r < 4; ++r) {
        s2r[r]     = s2g[4 * g + r];      c2r[r]     = c2g[4 * g + r];
        s2r[4 + r] = s2g[16 + 4 * g + r]; c2r[4 + r] = c2g[16 + 4 * g + r];
    }

    f32x4 accB[8];
#pragma unroll
    for (int dt = 0; dt < 8; ++dt) accB[dt] = (f32x4){0.f, 0.f, 0.f, 0.f};
    float asum_acc[8] = {0.f, 0.f, 0.f, 0.f, 0.f, 0.f, 0.f, 0.f};

    // prologue: issue subtile-0 loads
    float4 va[16];
    {
        const float* bp = xg + (size_t)rg * NN + 4 * c4;
#pragma unroll
        for (int j = 0; j < 16; ++j) va[j] = *(const float4*)(bp + (size_t)(j * 32) * NN);
    }

#pragma unroll
    for (int s = 0; s < SUBT; ++s) {
        u16* buf = (s & 1) ? xb1 : xb0;

        // a) convert va -> LDS (swizzled) + x2 partials
        {
            float p0 = 0, p1 = 0, p2 = 0, p3 = 0;
#pragma unroll
            for (int j = 0; j < 16; ++j) {
                const int d = j * 32 + rg;
                uint2 pk;
                pk.x = f2bf(va[j].x) | (f2bf(va[j].y) << 16);
                pk.y = f2bf(va[j].z) | (f2bf(va[j].w) << 16);
                *(uint2*)(buf + xidx(d, 4 * c4)) = pk;
                p0 += va[j].x * va[j].x; p1 += va[j].y * va[j].y;
                p2 += va[j].z * va[j].z; p3 += va[j].w * va[j].w;
            }
            p0 += __shfl_xor(p0, 16); p0 += __shfl_xor(p0, 32);
            p1 += __shfl_xor(p1, 16); p1 += __shfl_xor(p1, 32);
            p2 += __shfl_xor(p2, 16); p2 += __shfl_xor(p2, 32);
            p3 += __shfl_xor(p3, 16); p3 += __shfl_xor(p3, 32);
            if (l < 16) {
                x2_part[w * TNS + 4 * l + 0] = p0;
                x2_part[w * TNS + 4 * l + 1] = p1;
                x2_part[w * TNS + 4 * l + 2] = p2;
                x2_part[w * TNS + 4 * l + 3] = p3;
            }
        }
        __syncthreads();

        // b) issue next subtile's loads (fly under phase A/softmax/B)
        if (s < SUBT - 1) {
            const float* bp = xg + (s + 1) * TNS + (size_t)rg * NN + 4 * c4;
#pragma unroll
            for (int j = 0; j < 16; ++j) va[j] = *(const float4*)(bp + (size_t)(j * 32) * NN);
        }

        // c) phase A (waves 0-3): logits = c . x ; wave 4: x2 finalize
        f32x4 accA0 = {0.f, 0.f, 0.f, 0.f}, accA1 = {0.f, 0.f, 0.f, 0.f};
        if (w < 4) {
            const int nloc = w * 16 + li;
            for (int ch = 0; ch < 16; ++ch) {
                const int dbase = ch * 32 + g * 8;
                const u16* p = buf + xidx(dbase, nloc);
                short8v bf;
#pragma unroll
                for (int j = 0; j < 8; ++j) bf[j] = (short)p[j * ROWL];
                short8v a0 = *(const short8v*)(c_bf + li * DD + dbase);
                short8v a1 = *(const short8v*)(c_bf + (16 + li) * DD + dbase);
                accA0 = __builtin_amdgcn_mfma_f32_16x16x32_bf16(a0, bf, accA0, 0, 0, 0);
                accA1 = __builtin_amdgcn_mfma_f32_16x16x32_bf16(a1, bf, accA1, 0, 0, 0);
            }
        } else if (w == 4 && l < TNS) {
            float ssum = 0.f;
#pragma unroll
            for (int ww = 0; ww < 8; ++ww) ssum += x2_part[ww * TNS + l];
            x2[l] = ssum;
        }
        __syncthreads();

        // d) softmax (waves 0-3), write a_t bf16, accumulate asum in regs
        if (w < 4) {
            const int nloc = w * 16 + li;
            const float x2v = x2[nloc];
            float sl[8];
            float mx = -3.4e38f;
#pragma unroll
            for (int r = 0; r < 4; ++r) {
                float v0 = s2r[r]     * (x2v - 2.f * accA0[r] + c2r[r]);
                float v1 = s2r[4 + r] * (x2v - 2.f * accA1[r] + c2r[4 + r]);
                sl[r] = v0; sl[4 + r] = v1;
                mx = fmaxf(mx, fmaxf(v0, v1));
            }
            mx = fmaxf(mx, __shfl_xor(mx, 16));
            mx = fmaxf(mx, __shfl_xor(mx, 32));
            float sum = 0.f;
#pragma unroll
            for (int i = 0; i < 8; ++i) { sl[i] = __expf(sl[i] - mx); sum += sl[i]; }
            sum += __shfl_xor(sum, 16);
            sum += __shfl_xor(sum, 32);
            const float inv = 1.f / sum;
#pragma unroll
            for (int i = 0; i < 8; ++i) {
                float a = sl[i] * inv;
                int k = (i < 4) ? (4 * g + i) : (16 + 4 * g + (i - 4));
                a_t[k * ROWA + nloc] = (u16)f2bf(a);
                float ssum = a;
                ssum += __shfl_xor(ssum, 1); ssum += __shfl_xor(ssum, 2);
                ssum += __shfl_xor(ssum, 4); ssum += __shfl_xor(ssum, 8);
                asum_acc[i] += ssum;    // valid on li==0
            }
        }
        __syncthreads();

        // e) phase B (all 8 waves): accumulate e[k-tile][128 d per wave]
        {
            const int kt = w >> 2, dblk = w & 3;
#pragma unroll
            for (int ch = 0; ch < 2; ++ch) {
                const int nb = ch * 32 + g * 8;
                short8v af = *(const short8v*)(a_t + (kt * 16 + li) * ROWA + nb);
#pragma unroll
                for (int dt = 0; dt < 8; ++dt) {
                    const int d = dblk * 128 + dt * 16 + li;
                    short8v xf = *(const short8v*)(buf + xidx(d, nb));
                    accB[dt] = __builtin_amdgcn_mfma_f32_16x16x32_bf16(af, xf, accB[dt], 0, 0, 0);
                }
            }
        }
    }

    // ---- asum -> ws ----
    if (w < 4 && li == 0) {
#pragma unroll
        for (int i = 0; i < 8; ++i) {
            int k = (i < 4) ? (4 * g + i) : (16 + 4 * g + (i - 4));
            asum_p[w * KK + k] = asum_acc[i];
        }
    }
    __syncthreads();
    if (t < KK) {
        float s = 0.f;
#pragma unroll
        for (int ww = 0; ww < 4; ++ww) s += asum_p[ww * KK + t];
        ws_asum[(size_t)blk * KK + t] = s;
    }

    // ---- e partials -> ws (once per block) ----
    {
        const int kt = w >> 2, dblk = w & 3;
        const size_t ebase = (size_t)blk * KK * DD;
#pragma unroll
        for (int dt = 0; dt < 8; ++dt)
#pragma unroll
            for (int r = 0; r < 4; ++r) {
                int k = kt * 16 + 4 * g + r;
                int d = dblk * 128 + dt * 16 + li;
                ws_e[ebase + (size_t)k * DD + d] = (PART)(accB[dt][r]);
            }
    }
}

// ---------------- K2: reduce 16 partials, subtract asum*c ----------------
__global__ void k2_reduce_h(const __half2* __restrict__ ws_e, const float* __restrict__ ws_asum,
                            const float* __restrict__ cw, float* __restrict__ out) {
    int tid = blockIdx.x * blockDim.x + threadIdx.x;   // 131072
    int d2 = tid & 255;
    int k = (tid >> 8) & (KK - 1);
    int b = tid >> 13;
    const __half2* pe = ws_e + ((size_t)(b * NGRP) * KK + k) * 256 + d2;
    const float* pa = ws_asum + b * NGRP * KK + k;
    float s0 = 0.f, s1 = 0.f, as = 0.f;
#pragma unroll
    for (int tl = 0; tl < NGRP; ++tl) {
        float2 f = __half22float2(pe[(size_t)tl * KK * 256]);
        s0 += f.x; s1 += f.y;
        as += pa[tl * KK];
    }
    int d = d2 * 2;
    float c0 = cw[k * DD + d], c1 = cw[k * DD + d + 1];
    float2 o; o.x = s0 - as * c0; o.y = s1 - as * c1;
    *(float2*)(out + ((size_t)(b * KK + k) * DD + d)) = o;
}

__global__ void k2_reduce_f(const float* __restrict__ ws_e, const float* __restrict__ ws_asum,
                            const float* __restrict__ cw, float* __restrict__ out) {
    int tid = blockIdx.x * blockDim.x + threadIdx.x;   // 262144
    int d = tid & (DD - 1);
    int k = (tid >> 9) & (KK - 1);
    int b = tid >> 14;
    float s = 0.f, as = 0.f;
#pragma unroll
    for (int tl = 0; tl < NGRP; ++tl) {
        int blk = b * NGRP + tl;
        s += ws_e[((size_t)blk * KK + k) * DD + d];
        as += ws_asum[(size_t)blk * KK + k];
    }
    out[tid] = s - as * cw[k * DD + d];
}

extern "C" void kernel_launch(void* const* d_in, const int* in_sizes, int n_in,
                              void* d_out, int out_size, void* d_ws, size_t ws_size,
                              hipStream_t stream) {
    const float* x = (const float*)d_in[0];
    const float* cw = (const float*)d_in[1];
    const float* scale = (const float*)d_in[2];
    float* out = (float*)d_out;

    char* ws = (char*)d_ws;
    u16*   c_bf    = (u16*)ws;                  // 32768 B
    float* c2      = (float*)(ws + 32768);
    float* s2      = (float*)(ws + 32896);
    float* ws_asum = (float*)(ws + 33024);      // 256*32*4 = 32768 B
    char*  e_ptr   = ws + 65792;

    const size_t lds = (size_t)(2 * XBUF + KK * ROWA) * 2
                     + (8 * TNS + TNS + 4 * KK) * 4;   // 154880 B
    const size_t need_h = 65792 + (size_t)NBLK * KK * DD * sizeof(__half);

    k0_prep<<<KK, 64, 0, stream>>>(cw, scale, c_bf, c2, s2);
    if (ws_size >= need_h) {
        k1_fused<__half><<<NBLK, 512, lds, stream>>>(x, c_bf, c2, s2, ws_asum, (__half*)e_ptr);
        k2_reduce_h<<<(BB * KK * 256) / 256, 256, 0, stream>>>((const __half2*)e_ptr, ws_asum, cw, out);
    } else {
        k1_fused<float><<<NBLK, 512, lds, stream>>>(x, c_bf, c2, s2, ws_asum, (float*)e_ptr);
        k2_reduce_f<<<(BB * KK * DD) / 256, 256, 0, stream>>>((const float*)e_ptr, ws_asum, cw, out);
    }
}

// Round 6
// 47.806 us; speedup vs baseline: 1.2991x; 1.2136x over previous
//
#include <hip/hip_runtime.h>
#include <hip/hip_fp16.h>

#define BB 16
#define DD 512
#define NN 4096
#define KK 32
#define TNS 32          // n per subtile
#define SUBT 8          // subtiles per block (block owns 256 n)
#define NGRP 16         // n-groups (blocks) per batch
#define NBLK (BB*NGRP)  // 256 blocks
#define ROWX 40         // xbuf row length (bf16 elems), 80 B, b128-aligned
#define ROWA 40         // a_t row length

// LDS byte offsets
#define OFF_STAGE 0            // f32 stage [2 halves][256 d][32 n] = 65536
#define OFF_XBUF  65536        // bf16 [512][40] = 40960
#define OFF_CLDS  106496       // bf16 c swizzled [32][512] = 32768
#define OFF_AT    139264       // bf16 [32][40] = 2560
#define OFF_X2P   141824       // f32 [16][32] = 2048
#define OFF_X2    143872       // f32 [32]
#define OFF_S2    144000       // f32 [32]
#define OFF_C2    144128       // f32 [32]
#define OFF_ASUM  144256       // f32 [2][32]
#define LDS_TOTAL 144512

typedef unsigned short u16;
typedef __attribute__((ext_vector_type(8))) short short8v;
typedef __attribute__((ext_vector_type(4))) float f32x4;

#define SYNCL() asm volatile("s_waitcnt lgkmcnt(0)\n\ts_barrier" ::: "memory")

__device__ __forceinline__ unsigned f2bf(float f) {
    union { float f; unsigned u; } v; v.f = f;
    unsigned r = v.u + 0x7fff + ((v.u >> 16) & 1);   // RNE
    return r >> 16;
}

__device__ __forceinline__ void gload16(const float* src, char* lds) {
    __builtin_amdgcn_global_load_lds(
        (const __attribute__((address_space(1))) void*)src,
        (__attribute__((address_space(3))) void*)lds, 16, 0, 0);
}

// ---------------- K0: prep codewords (bf16 copy, c2, s2); 1 wave per k ----
__global__ void k0_prep(const float* __restrict__ cw, const float* __restrict__ scale,
                        u16* __restrict__ c_bf, float* __restrict__ c2,
                        float* __restrict__ s2) {
    const int k = blockIdx.x;       // 32 blocks
    const int l = threadIdx.x;      // 64 threads
    const float* row = cw + k * DD;
    float s = 0.f;
#pragma unroll
    for (int j = 0; j < 8; ++j) {
        float v = row[j * 64 + l];
        s += v * v;
        c_bf[k * DD + j * 64 + l] = (u16)f2bf(v);
    }
#pragma unroll
    for (int off = 32; off; off >>= 1) s += __shfl_xor(s, off);
    if (l == 0) { c2[k] = s; float sc = scale[k]; s2[k] = sc * sc; }
}

// ---------------- K1: fused, async-pipelined ----------------
template <typename PART>
__global__ __launch_bounds__(512)
void k1_fused(const float* __restrict__ x, const u16* __restrict__ c_bf,
              const float* __restrict__ c2g, const float* __restrict__ s2g,
              float* __restrict__ ws_asum, PART* __restrict__ ws_e) {
    extern __shared__ char smem[];
    float* stg     = (float*)(smem + OFF_STAGE);
    u16*   xbuf    = (u16*)(smem + OFF_XBUF);
    u16*   c_lds   = (u16*)(smem + OFF_CLDS);
    u16*   a_t     = (u16*)(smem + OFF_AT);
    float* x2_part = (float*)(smem + OFF_X2P);
    float* x2      = (float*)(smem + OFF_X2);
    float* s2_l    = (float*)(smem + OFF_S2);
    float* c2_l    = (float*)(smem + OFF_C2);
    float* asum_p  = (float*)(smem + OFF_ASUM);

    const int t = threadIdx.x;
    const int l = t & 63, w = t >> 6;        // lane, wave (8 waves)
    const int g = l >> 4, li = l & 15;       // 16-lane group, group-lane
    const int blk = blockIdx.x;
    const int b = blk >> 4, grp = blk & 15;
    const int n0 = grp * 256;
    const float* xg = x + (size_t)b * DD * NN + n0;

    // ---- prologue: c -> LDS (swizzled), s2/c2 -> LDS ----
    {
        const int k = t >> 4, seg = t & 15;
#pragma unroll
        for (int j = 0; j < 4; ++j) {
            const int dch = seg * 4 + j;
            short8v v = *(const short8v*)(c_bf + k * DD + dch * 8);
            *(short8v*)(c_lds + k * DD + ((dch ^ (k & 7)) << 3)) = v;
        }
        if (t < KK) { s2_l[t] = s2g[t]; c2_l[t] = c2g[t]; }
    }
    SYNCL();

    // per-lane softmax constants from LDS
    float s2r[8], c2r[8];
#pragma unroll
    for (int r = 0; r < 4; ++r) {
        s2r[r]     = s2_l[4 * g + r];      c2r[r]     = c2_l[4 * g + r];
        s2r[4 + r] = s2_l[16 + 4 * g + r]; c2r[4 + r] = c2_l[16 + 4 * g + r];
    }

    f32x4 accB[8];
#pragma unroll
    for (int dt = 0; dt < 8; ++dt) accB[dt] = (f32x4){0.f, 0.f, 0.f, 0.f};
    float asum_acc[8] = {0.f, 0.f, 0.f, 0.f, 0.f, 0.f, 0.f, 0.f};

    // staging geometry: per wave-inst (w,i): 1 KB LDS = rows w*32+i*8+(lane>>3)
    const int srow = w * 32 + (l >> 3);      // + i*8
    const int scol = (l & 7) * 4;            // float col within 32

    // issue subtile 0, both halves (8 insts -> vmcnt 8)
#pragma unroll
    for (int i = 0; i < 4; ++i)
        gload16(xg + (size_t)(srow + i * 8) * NN + scol,
                smem + OFF_STAGE + (w * 4 + i) * 1024);
#pragma unroll
    for (int i = 0; i < 4; ++i)
        gload16(xg + (size_t)(256 + srow + i * 8) * NN + scol,
                smem + OFF_STAGE + 32768 + (w * 4 + i) * 1024);

    const int cn = t & 31, cs = t >> 5;      // convert: col n, seg

    for (int s = 0; s < SUBT; ++s) {
        const int nbase = s * TNS;

        // ---- wait h0(s); sync (also: everyone done with xbuf/a_t of s-1) ----
        asm volatile("s_waitcnt vmcnt(4)" ::: "memory");
        __builtin_amdgcn_sched_barrier(0);
        SYNCL();

        // ---- convert half 0 (cols, conflict-free) ----
        float x2p = 0.f;
#pragma unroll
        for (int j = 0; j < 16; ++j) {
            const int d = cs * 16 + j;
            float v = stg[d * 32 + cn];
            x2p += v * v;
            const int chnk = (cn >> 3) ^ ((d >> 3) & 3);
            xbuf[d * ROWX + chnk * 8 + (cn & 7)] = (u16)f2bf(v);
        }
        SYNCL();   // stage-h0 reads retired everywhere

        if (s < SUBT - 1) {
#pragma unroll
            for (int i = 0; i < 4; ++i)
                gload16(xg + (size_t)(srow + i * 8) * NN + nbase + TNS + scol,
                        smem + OFF_STAGE + (w * 4 + i) * 1024);
        }

        // ---- wait h1(s) ----
        if (s < SUBT - 1) asm volatile("s_waitcnt vmcnt(4)" ::: "memory");
        else              asm volatile("s_waitcnt vmcnt(0)" ::: "memory");
        __builtin_amdgcn_sched_barrier(0);
        SYNCL();

        // ---- convert half 1 ----
#pragma unroll
        for (int j = 0; j < 16; ++j) {
            const int d = 256 + cs * 16 + j;
            float v = stg[8192 + (cs * 16 + j) * 32 + cn];
            x2p += v * v;
            const int chnk = (cn >> 3) ^ ((d >> 3) & 3);
            xbuf[d * ROWX + chnk * 8 + (cn & 7)] = (u16)f2bf(v);
        }
        x2_part[cs * 32 + cn] = x2p;
        SYNCL();   // stage-h1 reads retired; xbuf + x2_part visible

        if (s < SUBT - 1) {
#pragma unroll
            for (int i = 0; i < 4; ++i)
                gload16(xg + (size_t)(256 + srow + i * 8) * NN + nbase + TNS + scol,
                        smem + OFF_STAGE + 32768 + (w * 4 + i) * 1024);
        }

        // ---- phase A (waves 0-1): logits = c . x ; wave 2: x2 finalize ----
        f32x4 accA0 = {0.f, 0.f, 0.f, 0.f}, accA1 = {0.f, 0.f, 0.f, 0.f};
        if (w < 2) {
            const int nloc = w * 16 + li;
            const int nc = nloc >> 3, nr = nloc & 7;
            for (int ch = 0; ch < 16; ++ch) {
                const int dbase = ch * 32 + g * 8;
                const int chnk = (nc ^ g) & 3;
                short8v bf;
#pragma unroll
                for (int j = 0; j < 8; ++j)
                    bf[j] = (short)xbuf[(dbase + j) * ROWX + chnk * 8 + nr];
                const int csw = ((ch * 4 + g) ^ (li & 7)) << 3;
                short8v a0 = *(const short8v*)(c_lds + li * DD + csw);
                short8v a1 = *(const short8v*)(c_lds + (16 + li) * DD + csw);
                accA0 = __builtin_amdgcn_mfma_f32_16x16x32_bf16(a0, bf, accA0, 0, 0, 0);
                accA1 = __builtin_amdgcn_mfma_f32_16x16x32_bf16(a1, bf, accA1, 0, 0, 0);
            }
        } else if (w == 2 && l < TNS) {
            float ssum = 0.f;
#pragma unroll
            for (int sg = 0; sg < 16; ++sg) ssum += x2_part[sg * 32 + l];
            x2[l] = ssum;
        }
        SYNCL();   // x2 ready

        // ---- softmax (waves 0-1); write a_t; accumulate asum ----
        if (w < 2) {
            const int nloc = w * 16 + li;
            const float x2v = x2[nloc];
            float sl[8];
            float mx = -3.4e38f;
#pragma unroll
            for (int r = 0; r < 4; ++r) {
                float v0 = s2r[r]     * (x2v - 2.f * accA0[r] + c2r[r]);
                float v1 = s2r[4 + r] * (x2v - 2.f * accA1[r] + c2r[4 + r]);
                sl[r] = v0; sl[4 + r] = v1;
                mx = fmaxf(mx, fmaxf(v0, v1));
            }
            mx = fmaxf(mx, __shfl_xor(mx, 16));
            mx = fmaxf(mx, __shfl_xor(mx, 32));
            float sum = 0.f;
#pragma unroll
            for (int i = 0; i < 8; ++i) { sl[i] = __expf(sl[i] - mx); sum += sl[i]; }
            sum += __shfl_xor(sum, 16);
            sum += __shfl_xor(sum, 32);
            const float inv = 1.f / sum;
#pragma unroll
            for (int i = 0; i < 8; ++i) {
                float a = sl[i] * inv;
                int k = (i < 4) ? (4 * g + i) : (16 + 4 * g + (i - 4));
                a_t[k * ROWA + nloc] = (u16)f2bf(a);
                float ssum = a;
                ssum += __shfl_xor(ssum, 1); ssum += __shfl_xor(ssum, 2);
                ssum += __shfl_xor(ssum, 4); ssum += __shfl_xor(ssum, 8);
                asum_acc[i] += ssum;
            }
        }
        SYNCL();   // a_t ready

        // ---- phase B (all 8 waves): accumulate e[k-tile][128 d per wave] ----
        {
            const int kt = w >> 2, dblk = w & 3;
            short8v af = *(const short8v*)(a_t + (kt * 16 + li) * ROWA + g * 8);
#pragma unroll
            for (int dt = 0; dt < 8; ++dt) {
                const int d = dblk * 128 + dt * 16 + li;
                const int chnk = (g ^ ((d >> 3) & 3)) & 3;
                short8v xf = *(const short8v*)(xbuf + d * ROWX + chnk * 8);
                accB[dt] = __builtin_amdgcn_mfma_f32_16x16x32_bf16(af, xf, accB[dt], 0, 0, 0);
            }
        }
        // no trailing barrier: next iteration's head SYNCL covers it
    }

    __syncthreads();

    // ---- asum -> ws ----
    if (w < 2 && li == 0) {
#pragma unroll
        for (int i = 0; i < 8; ++i) {
            int k = (i < 4) ? (4 * g + i) : (16 + 4 * g + (i - 4));
            asum_p[w * KK + k] = asum_acc[i];
        }
    }
    __syncthreads();
    if (t < KK) ws_asum[(size_t)blk * KK + t] = asum_p[t] + asum_p[KK + t];

    // ---- e partials -> ws (once per block) ----
    {
        const int kt = w >> 2, dblk = w & 3;
        const size_t ebase = (size_t)blk * KK * DD;
#pragma unroll
        for (int dt = 0; dt < 8; ++dt)
#pragma unroll
            for (int r = 0; r < 4; ++r) {
                int k = kt * 16 + 4 * g + r;
                int d = dblk * 128 + dt * 16 + li;
                ws_e[ebase + (size_t)k * DD + d] = (PART)(accB[dt][r]);
            }
    }
}

// ---------------- K2: reduce 16 partials, subtract asum*c ----------------
__global__ void k2_reduce_h(const __half2* __restrict__ ws_e, const float* __restrict__ ws_asum,
                            const float* __restrict__ cw, float* __restrict__ out) {
    int tid = blockIdx.x * blockDim.x + threadIdx.x;   // 131072
    int d2 = tid & 255;
    int k = (tid >> 8) & (KK - 1);
    int b = tid >> 13;
    const __half2* pe = ws_e + ((size_t)(b * NGRP) * KK + k) * 256 + d2;
    const float* pa = ws_asum + b * NGRP * KK + k;
    float s0 = 0.f, s1 = 0.f, as = 0.f;
#pragma unroll
    for (int tl = 0; tl < NGRP; ++tl) {
        float2 f = __half22float2(pe[(size_t)tl * KK * 256]);
        s0 += f.x; s1 += f.y;
        as += pa[tl * KK];
    }
    int d = d2 * 2;
    float c0 = cw[k * DD + d], c1 = cw[k * DD + d + 1];
    float2 o; o.x = s0 - as * c0; o.y = s1 - as * c1;
    *(float2*)(out + ((size_t)(b * KK + k) * DD + d)) = o;
}

__global__ void k2_reduce_f(const float* __restrict__ ws_e, const float* __restrict__ ws_asum,
                            const float* __restrict__ cw, float* __restrict__ out) {
    int tid = blockIdx.x * blockDim.x + threadIdx.x;   // 262144
    int d = tid & (DD - 1);
    int k = (tid >> 9) & (KK - 1);
    int b = tid >> 14;
    float s = 0.f, as = 0.f;
#pragma unroll
    for (int tl = 0; tl < NGRP; ++tl) {
        int blk = b * NGRP + tl;
        s += ws_e[((size_t)blk * KK + k) * DD + d];
        as += ws_asum[(size_t)blk * KK + k];
    }
    out[tid] = s - as * cw[k * DD + d];
}

extern "C" void kernel_launch(void* const* d_in, const int* in_sizes, int n_in,
                              void* d_out, int out_size, void* d_ws, size_t ws_size,
                              hipStream_t stream) {
    const float* x = (const float*)d_in[0];
    const float* cw = (const float*)d_in[1];
    const float* scale = (const float*)d_in[2];
    float* out = (float*)d_out;

    char* ws = (char*)d_ws;
    u16*   c_bf    = (u16*)ws;                  // 32768 B
    float* c2      = (float*)(ws + 32768);
    float* s2      = (float*)(ws + 32896);
    float* ws_asum = (float*)(ws + 33024);      // 256*32*4 = 32768 B
    char*  e_ptr   = ws + 65792;

    const size_t need_h = 65792 + (size_t)NBLK * KK * DD * sizeof(__half);

    k0_prep<<<KK, 64, 0, stream>>>(cw, scale, c_bf, c2, s2);
    if (ws_size >= need_h) {
        k1_fused<__half><<<NBLK, 512, LDS_TOTAL, stream>>>(x, c_bf, c2, s2, ws_asum, (__half*)e_ptr);
        k2_reduce_h<<<(BB * KK * 256) / 256, 256, 0, stream>>>((const __half2*)e_ptr, ws_asum, cw, out);
    } else {
        k1_fused<float><<<NBLK, 512, LDS_TOTAL, stream>>>(x, c_bf, c2, s2, ws_asum, (float*)e_ptr);
        k2_reduce_f<<<(BB * KK * DD) / 256, 256, 0, stream>>>((const float*)e_ptr, ws_asum, cw, out);
    }
}